// Round 2
// baseline (18984.279 us; speedup 1.0000x reference)
//
#include <hip/hip_runtime.h>
#include <math.h>

#define HID 256
#define TT  256
#define BB  512          // batch
#define NB  256          // blocks (1 per CU)
#define NT  512          // threads per block (8 waves)
#define RPB 64           // batch rows per block
#define CPB 32           // gate-cols per block
#define HPB 8            // hidden units per block

// ws layout (float offsets)
#define OFF_AHH0 0
#define OFF_AIH1 262144
#define OFF_AHH1 524288
#define OFF_AIH0 786432                 // 10*1024
#define OFF_H0   1048576                // [2][512][256]
#define OFF_H1   (1048576 + 262144)
#define OFF_BAR  (1048576 + 524288)     // unsigned counter

// ---------------------------------------------------------------------------
// W [1024][K] row-major -> A [K][1024] gate-interleaved: A[kk][ku*4+g]
// ---------------------------------------------------------------------------
__global__ void transpose_gi(const float* __restrict__ W, float* __restrict__ A, int K) {
    int idx = blockIdx.x * 256 + threadIdx.x;
    if (idx < K * 1024) {
        int kk = idx >> 10;
        int r  = idx & 1023;
        int k  = r >> 2;
        int g  = r & 3;
        A[idx] = W[(g * 256 + k) * K + kk];
    }
}

__device__ __forceinline__ float sigf(float x)      { return 1.0f / (1.0f + __expf(-x)); }
__device__ __forceinline__ float tanhfast(float x)  { return 1.0f - 2.0f / (__expf(2.0f * x) + 1.0f); }
__device__ __forceinline__ void fma4(float4& a, const float4& w, float h) {
    a.x += w.x * h; a.y += w.y * h; a.z += w.z * h; a.w += w.w * h;
}

// ---------------------------------------------------------------------------
__global__ __launch_bounds__(512, 2)
void lstm_coop(const float* __restrict__ x,
               const float* __restrict__ bih0, const float* __restrict__ bhh0,
               const float* __restrict__ bih1, const float* __restrict__ bhh1,
               const float* __restrict__ Wlin, const float* __restrict__ blin,
               float* __restrict__ ws, float* __restrict__ out)
{
    // one shared array; manual offsets (red overlays h0s/h1s)
    __shared__ float smem[16448 * 2 + 704 + 64];
    float* h0s = smem;                 // [64][257]
    float* h1s = smem + 16448;         // [64][257]
    float* xs  = smem + 32896;         // [64][11]
    float* bb  = smem + 33600;         // bias0[32] | bias1[32]
    float* red = smem;                 // [4][64][65] = 16640 floats (overlay, used after GEMM)

    const int tid  = threadIdx.x;
    const int lane = tid & 63;                                        // row in tile
    const int w    = __builtin_amdgcn_readfirstlane(tid >> 6);        // wave id 0..7 (K-group)
    const int ib   = blockIdx.x & 7;                                  // row-group (XCD-aligned)
    const int ik   = blockIdx.x >> 3;                                 // col-slice 0..31
    const int rb0  = ib * RPB;

    const float* Ahh0 = ws + OFF_AHH0 + ik * CPB;
    const float* Aih1 = ws + OFF_AIH1 + ik * CPB;
    const float* Ahh1 = ws + OFF_AHH1 + ik * CPB;
    const float* Aih0 = ws + OFF_AIH0 + ik * CPB;
    float* gh0 = ws + OFF_H0;
    float* gh1 = ws + OFF_H1;
    unsigned* bar = (unsigned*)(ws + OFF_BAR);

    // biases (gate-interleaved per local col)
    if (tid < 64) {
        int half = tid >> 5, c = tid & 31, u = c >> 2, g = c & 3;
        int idx = g * 256 + ik * HPB + u;
        bb[tid] = half ? (bih1[idx] + bhh1[idx]) : (bih0[idx] + bhh0[idx]);
    }

    float c0r[8], c1r[8];
    #pragma unroll
    for (int u = 0; u < 8; ++u) { c0r[u] = 0.f; c1r[u] = 0.f; }

    const int kbase = w * 32;

    for (int e = 0; e <= TT; ++e) {
        // ---------------- stage h0[e-1], h1[e-2], x[t] into LDS ----------------
        {
            const float4* s0 = (const float4*)(gh0 + (size_t)((e + 1) & 1) * (BB * HID) + (size_t)rb0 * HID);
            const float4* s1 = (const float4*)(gh1 + (size_t)(e & 1)       * (BB * HID) + (size_t)rb0 * HID);
            #pragma unroll
            for (int p = 0; p < 8; ++p) {
                int idx4 = tid + p * NT;            // 0..4095
                float4 v0 = s0[idx4];
                float4 v1 = s1[idx4];
                int r  = idx4 >> 6;
                int kk = (idx4 & 63) << 2;
                int la = r * 257 + kk;
                h0s[la] = v0.x; h0s[la + 1] = v0.y; h0s[la + 2] = v0.z; h0s[la + 3] = v0.w;
                h1s[la] = v1.x; h1s[la + 1] = v1.y; h1s[la + 2] = v1.z; h1s[la + 3] = v1.w;
            }
            int t = (e < TT) ? e : (TT - 1);
            for (int tau = tid; tau < 640; tau += NT) {
                int r = tau / 10, i = tau - r * 10;
                xs[r * 11 + i] = x[(size_t)(rb0 + r) * (TT * 10) + t * 10 + i];
            }
        }
        __syncthreads();

        // ---------------- GEMM partials (wave w covers kk in [32w, 32w+32)) ----
        float4 a0[8], a1[8];
        #pragma unroll
        for (int c = 0; c < 8; ++c) {
            a0[c] = make_float4(0.f, 0.f, 0.f, 0.f);
            a1[c] = make_float4(0.f, 0.f, 0.f, 0.f);
        }
        #pragma unroll 2
        for (int j = 0; j < 32; ++j) {
            int kk = kbase + j;
            float h0v = h0s[lane * 257 + kk];
            float h1v = h1s[lane * 257 + kk];
            const float4* r0 = (const float4*)(Ahh0 + (size_t)kk * 1024);
            const float4* r1 = (const float4*)(Aih1 + (size_t)kk * 1024);
            const float4* r2 = (const float4*)(Ahh1 + (size_t)kk * 1024);
            #pragma unroll
            for (int c = 0; c < 8; ++c) {
                fma4(a0[c], r0[c], h0v);
                fma4(a1[c], r1[c], h0v);
                fma4(a1[c], r2[c], h1v);
            }
        }
        if (w == 7) {  // layer-0 input contribution (K=10)
            #pragma unroll
            for (int i = 0; i < 10; ++i) {
                float xv = xs[lane * 11 + i];
                const float4* ri = (const float4*)(Aih0 + (size_t)i * 1024);
                #pragma unroll
                for (int c = 0; c < 8; ++c) fma4(a0[c], ri[c], xv);
            }
        }
        __syncthreads();   // GEMM done; h LDS now dead (red overlay OK)

        // ---------------- cross-wave K reduction (8 -> 4 -> 2 -> 1) ------------
        if (w >= 4) {
            float* d = red + ((w - 4) * 64 + lane) * 65;
            #pragma unroll
            for (int c = 0; c < 8; ++c) {
                d[4*c] = a0[c].x; d[4*c+1] = a0[c].y; d[4*c+2] = a0[c].z; d[4*c+3] = a0[c].w;
                d[32+4*c] = a1[c].x; d[32+4*c+1] = a1[c].y; d[32+4*c+2] = a1[c].z; d[32+4*c+3] = a1[c].w;
            }
        }
        __syncthreads();
        if (w < 4) {
            const float* s = red + (w * 64 + lane) * 65;
            #pragma unroll
            for (int c = 0; c < 8; ++c) {
                a0[c].x += s[4*c]; a0[c].y += s[4*c+1]; a0[c].z += s[4*c+2]; a0[c].w += s[4*c+3];
                a1[c].x += s[32+4*c]; a1[c].y += s[32+4*c+1]; a1[c].z += s[32+4*c+2]; a1[c].w += s[32+4*c+3];
            }
        }
        __syncthreads();
        if (w >= 2 && w < 4) {
            float* d = red + ((w - 2) * 64 + lane) * 65;
            #pragma unroll
            for (int c = 0; c < 8; ++c) {
                d[4*c] = a0[c].x; d[4*c+1] = a0[c].y; d[4*c+2] = a0[c].z; d[4*c+3] = a0[c].w;
                d[32+4*c] = a1[c].x; d[32+4*c+1] = a1[c].y; d[32+4*c+2] = a1[c].z; d[32+4*c+3] = a1[c].w;
            }
        }
        __syncthreads();
        if (w < 2) {
            const float* s = red + (w * 64 + lane) * 65;
            #pragma unroll
            for (int c = 0; c < 8; ++c) {
                a0[c].x += s[4*c]; a0[c].y += s[4*c+1]; a0[c].z += s[4*c+2]; a0[c].w += s[4*c+3];
                a1[c].x += s[32+4*c]; a1[c].y += s[32+4*c+1]; a1[c].z += s[32+4*c+2]; a1[c].w += s[32+4*c+3];
            }
        }
        __syncthreads();
        if (w == 1) {
            float* d = red + lane * 65;
            #pragma unroll
            for (int c = 0; c < 8; ++c) {
                d[4*c] = a0[c].x; d[4*c+1] = a0[c].y; d[4*c+2] = a0[c].z; d[4*c+3] = a0[c].w;
                d[32+4*c] = a1[c].x; d[32+4*c+1] = a1[c].y; d[32+4*c+2] = a1[c].z; d[32+4*c+3] = a1[c].w;
            }
        }
        __syncthreads();

        // ---------------- eltwise (wave 0 only; lane = row) --------------------
        if (w == 0) {
            const float* s = red + lane * 65;
            float* d0 = gh0 + (size_t)(e & 1)       * (BB * HID) + (size_t)(rb0 + lane) * HID + ik * HPB;
            float* d1 = gh1 + (size_t)((e + 1) & 1) * (BB * HID) + (size_t)(rb0 + lane) * HID + ik * HPB;
            #pragma unroll
            for (int u = 0; u < 8; ++u) {
                float gi = a0[u].x + s[4*u]     + bb[u*4+0];
                float gf = a0[u].y + s[4*u+1]   + bb[u*4+1];
                float gg = a0[u].z + s[4*u+2]   + bb[u*4+2];
                float go = a0[u].w + s[4*u+3]   + bb[u*4+3];
                float cn = sigf(gf) * c0r[u] + sigf(gi) * tanhfast(gg);
                c0r[u] = cn;
                d0[u] = sigf(go) * tanhfast(cn);
                if (e > 0) {
                    float hi = a1[u].x + s[32+4*u]   + bb[32+u*4+0];
                    float hf = a1[u].y + s[32+4*u+1] + bb[32+u*4+1];
                    float hg = a1[u].z + s[32+4*u+2] + bb[32+u*4+2];
                    float ho = a1[u].w + s[32+4*u+3] + bb[32+u*4+3];
                    float cn1 = sigf(hf) * c1r[u] + sigf(hi) * tanhfast(hg);
                    c1r[u] = cn1;
                    d1[u] = sigf(ho) * tanhfast(cn1);
                }
            }
        }

        // ---------------- device-wide barrier ----------------------------------
        __syncthreads();                 // drains vmcnt for ALL waves' stores
        if (tid == 0) {
            __threadfence();             // release: L2 writeback (agent scope)
            __hip_atomic_fetch_add(bar, 1u, __ATOMIC_RELAXED, __HIP_MEMORY_SCOPE_AGENT);
            unsigned target = (unsigned)(e + 1) * NB;
            while (__hip_atomic_load(bar, __ATOMIC_RELAXED, __HIP_MEMORY_SCOPE_AGENT) < target)
                __builtin_amdgcn_s_sleep(2);
            __threadfence();             // acquire: invalidate L1/L2
        }
        __syncthreads();
    }

    // ---------------- head: y[b] = h1[255] . Wlin + blin -----------------------
    if (ik == 0) {
        const float* hf = gh1 + (size_t)1 * (BB * HID);   // step 255 lives in slot 1
        int r = tid >> 3, kq = tid & 7;
        const float* hr = hf + (size_t)(rb0 + r) * HID + kq * 32;
        float sacc = 0.f;
        #pragma unroll
        for (int j = 0; j < 32; ++j) sacc += hr[j] * Wlin[kq * 32 + j];
        sacc += __shfl_down(sacc, 4, 8);
        sacc += __shfl_down(sacc, 2, 8);
        sacc += __shfl_down(sacc, 1, 8);
        if (kq == 0) out[rb0 + r] = sacc + blin[0];
    }
}

// ---------------------------------------------------------------------------
extern "C" void kernel_launch(void* const* d_in, const int* in_sizes, int n_in,
                              void* d_out, int out_size, void* d_ws, size_t ws_size,
                              hipStream_t stream) {
    const float* x     = (const float*)d_in[0];
    const float* W_ih0 = (const float*)d_in[1];
    const float* W_hh0 = (const float*)d_in[2];
    const float* b_ih0 = (const float*)d_in[3];
    const float* b_hh0 = (const float*)d_in[4];
    const float* W_ih1 = (const float*)d_in[5];
    const float* W_hh1 = (const float*)d_in[6];
    const float* b_ih1 = (const float*)d_in[7];
    const float* b_hh1 = (const float*)d_in[8];
    const float* W_lin = (const float*)d_in[9];
    const float* b_lin = (const float*)d_in[10];
    float* out = (float*)d_out;
    float* ws  = (float*)d_ws;

    // zero h-state ring buffers + barrier counter (ws is poisoned each launch)
    hipMemsetAsync((char*)d_ws + (size_t)OFF_H0 * 4, 0, (size_t)524288 * 4 + 256, stream);

    transpose_gi<<<1024, 256, 0, stream>>>(W_hh0, ws + OFF_AHH0, 256);
    transpose_gi<<<1024, 256, 0, stream>>>(W_ih1, ws + OFF_AIH1, 256);
    transpose_gi<<<1024, 256, 0, stream>>>(W_hh1, ws + OFF_AHH1, 256);
    transpose_gi<<<40,   256, 0, stream>>>(W_ih0, ws + OFF_AIH0, 10);

    lstm_coop<<<NB, NT, 0, stream>>>(x, b_ih0, b_hh0, b_ih1, b_hh1,
                                     W_lin, b_lin, ws, out);
}

// Round 3
// 17090.401 us; speedup vs baseline: 1.1108x; 1.1108x over previous
//
#include <hip/hip_runtime.h>
#include <math.h>

#define HID 256
#define TT  256
#define BB  512
#define NB  256
#define RPB 64       // batch rows per block
#define HPB 8        // hidden units per block (32 gate cols)

// float offsets in ws
#define OFF_AHH0 0
#define OFF_AIH1 262144
#define OFF_AHH1 524288
#define OFF_AIH0 786432
#define OFF_H0   802816                 // [2][512][256]
#define OFF_H1   1064960                // [2][512][256]
#define OFF_BAR  1327104                // unsigned counters (leaf[32] spread + root)

// ---------------------------------------------------------------------------
// W [1024][K] row-major -> A [K][1024] gate-interleaved: A[kk][hid*4+g]
// ---------------------------------------------------------------------------
__global__ void transpose_gi(const float* __restrict__ W, float* __restrict__ A, int K) {
    int idx = blockIdx.x * 256 + threadIdx.x;
    if (idx < K * 1024) {
        int kk = idx >> 10;
        int r  = idx & 1023;
        int k  = r >> 2;
        int g  = r & 3;
        A[idx] = W[(g * 256 + k) * K + kk];
    }
}

__device__ __forceinline__ float sigf(float x)     { return 1.0f / (1.0f + __expf(-x)); }
__device__ __forceinline__ float tanhfast(float x) { return 1.0f - 2.0f / (__expf(2.0f * x) + 1.0f); }

__device__ __forceinline__ float rlanef(float v, int l) {
    return __int_as_float(__builtin_amdgcn_readlane(__float_as_int(v), l));
}

// device-coherent (IF$-level) 8-byte load/store: bypass L1/L2, no fences needed
__device__ __forceinline__ float2 ldg_coh2(const float* p) {
    unsigned long long v = __hip_atomic_load((const unsigned long long*)p,
                                             __ATOMIC_RELAXED, __HIP_MEMORY_SCOPE_AGENT);
    float2 r;
    __builtin_memcpy(&r, &v, 8);
    return r;
}
__device__ __forceinline__ void stg_coh2(float* p, float a, float b) {
    float2 t; t.x = a; t.y = b;
    unsigned long long v;
    __builtin_memcpy(&v, &t, 8);
    __hip_atomic_store((unsigned long long*)p, v, __ATOMIC_RELAXED, __HIP_MEMORY_SCOPE_AGENT);
}

// ---------------------------------------------------------------------------
// Persistent fused 2-layer LSTM. 256 blocks (1/CU) x 256 threads (4 waves).
// Block (ib,ik): ib=blockIdx&7 -> 64 batch rows; ik=blockIdx>>3 -> 8 hidden units.
// Wave wv owns k-quarter [wv*64, wv*64+64): its weight slice lives in VGPRs
// (lane j holds all 96 gate-cols for k=wv*64+j); per-k broadcast via v_readlane.
// lane = batch row within tile. h exchanged through IF$ (agent-scope atomics),
// one grid barrier per timestep. Layer1 pipelined one step behind layer0.
// ---------------------------------------------------------------------------
__global__ __launch_bounds__(256, 1)
void lstm_pers(const float* __restrict__ x,
               const float* __restrict__ bih0, const float* __restrict__ bhh0,
               const float* __restrict__ bih1, const float* __restrict__ bhh1,
               const float* __restrict__ Wlin, const float* __restrict__ blin,
               float* __restrict__ ws, float* __restrict__ out)
{
    __shared__ __align__(16) float lds[9760];
    // [0,8704)    : per-wave h slabs (wv*2080 + j*65 + lane); overlaid after gemm by
    //               reduce scratch (row stride 68, b128 phase-conflict-free)
    // [8704,9354) : xslab [10][65] (wave3 private)
    // [9354,9418) : bias [64]  (layer0 32 | layer1 32, gate-interleaved)
    // [9418,9738) : Aih0 slice [10][32]

    const int tid  = threadIdx.x;
    const int lane = tid & 63;
    const int wv   = __builtin_amdgcn_readfirstlane(tid >> 6);
    const int ib   = blockIdx.x & 7;
    const int ik   = blockIdx.x >> 3;
    const int rb0  = ib * RPB;

    float* xslab = lds + 8704;
    float* lbias = lds + 9354;
    float* ldsX  = lds + 9418;

    const float* A0 = ws + OFF_AHH0;
    const float* A1 = ws + OFF_AIH1;
    const float* A2 = ws + OFF_AHH1;
    const float* AX = ws + OFF_AIH0;
    float* gh0 = ws + OFF_H0;
    float* gh1 = ws + OFF_H1;
    unsigned* bar = (unsigned*)(ws + OFF_BAR);

    // bias + Aih0 slice into LDS
    if (tid < 64) {
        int half = tid >> 5, c = tid & 31, u = c >> 2, g = c & 3;
        int idx = g * 256 + ik * HPB + u;
        lbias[tid] = half ? (bih1[idx] + bhh1[idx]) : (bih0[idx] + bhh0[idx]);
    }
    for (int n = tid; n < 320; n += 256)
        ldsX[n] = AX[(n >> 5) * 1024 + ik * 32 + (n & 31)];

    // persistent weight slice in VGPRs: lane j of wave wv holds k = wv*64+j
    const int kg = wv * 64 + lane;
    float4 wA[8], wB[8], wC[8];
    #pragma unroll
    for (int c4 = 0; c4 < 8; ++c4) {
        wA[c4] = *(const float4*)(A0 + (size_t)kg * 1024 + ik * 32 + c4 * 4);
        wB[c4] = *(const float4*)(A1 + (size_t)kg * 1024 + ik * 32 + c4 * 4);
        wC[c4] = *(const float4*)(A2 + (size_t)kg * 1024 + ik * 32 + c4 * 4);
    }
    __syncthreads();

    float c0s[8], c1s[8];
    #pragma unroll
    for (int u = 0; u < 8; ++u) { c0s[u] = 0.f; c1s[u] = 0.f; }

    float* slabW = lds + wv * 2080;

    for (int e = 0; e <= TT; ++e) {
        const bool doL0 = (e < TT), doL1 = (e > 0);
        float acc0[32], acc1[32];
        #pragma unroll
        for (int c = 0; c < 32; ++c) { acc0[c] = 0.f; acc1[c] = 0.f; }

        // ===== h0[e-1] phases (feeds gemm0: Ahh0, and gemm1: Aih1) =====
        const float* h0src = gh0 + (size_t)((e + 1) & 1) * 131072
                                 + (size_t)(rb0 + lane) * 256 + wv * 64;
        #pragma unroll 1
        for (int half = 0; half < 2; ++half) {
            const float* s = h0src + half * 32;
            #pragma unroll
            for (int m = 0; m < 16; ++m) {
                float2 v = ldg_coh2(s + 2 * m);
                slabW[(2 * m) * 65 + lane]     = v.x;
                slabW[(2 * m + 1) * 65 + lane] = v.y;
            }
            const int kbL = half * 32;
            #pragma unroll 1
            for (int j = 0; j < 32; ++j) {
                float h0v = slabW[j * 65 + lane];
                int rl = kbL + j;
                if (doL0) {
                    #pragma unroll
                    for (int c4 = 0; c4 < 8; ++c4) {
                        acc0[4 * c4 + 0] += rlanef(wA[c4].x, rl) * h0v;
                        acc0[4 * c4 + 1] += rlanef(wA[c4].y, rl) * h0v;
                        acc0[4 * c4 + 2] += rlanef(wA[c4].z, rl) * h0v;
                        acc0[4 * c4 + 3] += rlanef(wA[c4].w, rl) * h0v;
                    }
                }
                if (doL1) {
                    #pragma unroll
                    for (int c4 = 0; c4 < 8; ++c4) {
                        acc1[4 * c4 + 0] += rlanef(wB[c4].x, rl) * h0v;
                        acc1[4 * c4 + 1] += rlanef(wB[c4].y, rl) * h0v;
                        acc1[4 * c4 + 2] += rlanef(wB[c4].z, rl) * h0v;
                        acc1[4 * c4 + 3] += rlanef(wB[c4].w, rl) * h0v;
                    }
                }
            }
        }

        // ===== h1[e-2] phases (gemm2: Ahh1) =====
        if (doL1) {
            const float* h1src = gh1 + (size_t)(e & 1) * 131072
                                     + (size_t)(rb0 + lane) * 256 + wv * 64;
            #pragma unroll 1
            for (int half = 0; half < 2; ++half) {
                const float* s = h1src + half * 32;
                #pragma unroll
                for (int m = 0; m < 16; ++m) {
                    float2 v = ldg_coh2(s + 2 * m);
                    slabW[(2 * m) * 65 + lane]     = v.x;
                    slabW[(2 * m + 1) * 65 + lane] = v.y;
                }
                const int kbL = half * 32;
                #pragma unroll 1
                for (int j = 0; j < 32; ++j) {
                    float h1v = slabW[j * 65 + lane];
                    int rl = kbL + j;
                    #pragma unroll
                    for (int c4 = 0; c4 < 8; ++c4) {
                        acc1[4 * c4 + 0] += rlanef(wC[c4].x, rl) * h1v;
                        acc1[4 * c4 + 1] += rlanef(wC[c4].y, rl) * h1v;
                        acc1[4 * c4 + 2] += rlanef(wC[c4].z, rl) * h1v;
                        acc1[4 * c4 + 3] += rlanef(wC[c4].w, rl) * h1v;
                    }
                }
            }
        }

        // ===== x contribution (layer0, K=10) on wave3; x is L2-warm (no fences) =====
        if (doL0 && wv == 3) {
            const float* xsrc = x + (size_t)(rb0 + lane) * 2560 + e * 10;
            #pragma unroll
            for (int m = 0; m < 5; ++m) {
                float2 v = *(const float2*)(xsrc + 2 * m);
                xslab[(2 * m) * 65 + lane]     = v.x;
                xslab[(2 * m + 1) * 65 + lane] = v.y;
            }
            #pragma unroll 1
            for (int i = 0; i < 10; ++i) {
                float xv = xslab[i * 65 + lane];
                #pragma unroll
                for (int c4 = 0; c4 < 8; ++c4) {
                    float4 wx = *(const float4*)(ldsX + i * 32 + c4 * 4);
                    acc0[4 * c4 + 0] += wx.x * xv;
                    acc0[4 * c4 + 1] += wx.y * xv;
                    acc0[4 * c4 + 2] += wx.z * xv;
                    acc0[4 * c4 + 3] += wx.w * xv;
                }
            }
        }

        __syncthreads();   // gemms done; slabs dead -> reduce scratch overlay

        // ===== cross-wave k reduction 4 -> 2 -> 1 (scratch stride 68) =====
        if (wv >= 2) {
            float* d = lds + ((wv - 2) * 64 + lane) * 68;
            #pragma unroll
            for (int c4 = 0; c4 < 8; ++c4) {
                *(float4*)(d + 4 * c4)      = make_float4(acc0[4*c4], acc0[4*c4+1], acc0[4*c4+2], acc0[4*c4+3]);
                *(float4*)(d + 32 + 4 * c4) = make_float4(acc1[4*c4], acc1[4*c4+1], acc1[4*c4+2], acc1[4*c4+3]);
            }
        }
        __syncthreads();
        if (wv < 2) {
            const float* s2 = lds + (wv * 64 + lane) * 68;
            #pragma unroll
            for (int c4 = 0; c4 < 8; ++c4) {
                float4 t0 = *(const float4*)(s2 + 4 * c4);
                float4 t1 = *(const float4*)(s2 + 32 + 4 * c4);
                acc0[4*c4] += t0.x; acc0[4*c4+1] += t0.y; acc0[4*c4+2] += t0.z; acc0[4*c4+3] += t0.w;
                acc1[4*c4] += t1.x; acc1[4*c4+1] += t1.y; acc1[4*c4+2] += t1.z; acc1[4*c4+3] += t1.w;
            }
        }
        __syncthreads();
        if (wv == 1) {
            float* d = lds + lane * 68;
            #pragma unroll
            for (int c4 = 0; c4 < 8; ++c4) {
                *(float4*)(d + 4 * c4)      = make_float4(acc0[4*c4], acc0[4*c4+1], acc0[4*c4+2], acc0[4*c4+3]);
                *(float4*)(d + 32 + 4 * c4) = make_float4(acc1[4*c4], acc1[4*c4+1], acc1[4*c4+2], acc1[4*c4+3]);
            }
        }
        __syncthreads();
        if (wv == 0) {
            const float* s2 = lds + lane * 68;
            #pragma unroll
            for (int c4 = 0; c4 < 8; ++c4) {
                float4 t0 = *(const float4*)(s2 + 4 * c4);
                float4 t1 = *(const float4*)(s2 + 32 + 4 * c4);
                acc0[4*c4] += t0.x; acc0[4*c4+1] += t0.y; acc0[4*c4+2] += t0.z; acc0[4*c4+3] += t0.w;
                acc1[4*c4] += t1.x; acc1[4*c4+1] += t1.y; acc1[4*c4+2] += t1.z; acc1[4*c4+3] += t1.w;
            }

            // ===== eltwise (lane = row), c-state in registers =====
            float hn0[8], hn1[8];
            if (doL0) {
                #pragma unroll
                for (int u = 0; u < 8; ++u) {
                    float gi = acc0[u*4+0] + lbias[u*4+0];
                    float gf = acc0[u*4+1] + lbias[u*4+1];
                    float gg = acc0[u*4+2] + lbias[u*4+2];
                    float go = acc0[u*4+3] + lbias[u*4+3];
                    float cn = sigf(gf) * c0s[u] + sigf(gi) * tanhfast(gg);
                    c0s[u] = cn;
                    hn0[u] = sigf(go) * tanhfast(cn);
                }
            }
            if (doL1) {
                #pragma unroll
                for (int u = 0; u < 8; ++u) {
                    float gi = acc1[u*4+0] + lbias[32+u*4+0];
                    float gf = acc1[u*4+1] + lbias[32+u*4+1];
                    float gg = acc1[u*4+2] + lbias[32+u*4+2];
                    float go = acc1[u*4+3] + lbias[32+u*4+3];
                    float cn = sigf(gf) * c1s[u] + sigf(gi) * tanhfast(gg);
                    c1s[u] = cn;
                    hn1[u] = sigf(go) * tanhfast(cn);
                }
            }
            if (doL0) {
                float* d0 = gh0 + (size_t)(e & 1) * 131072 + (size_t)(rb0 + lane) * 256 + ik * HPB;
                #pragma unroll
                for (int q = 0; q < 4; ++q) stg_coh2(d0 + 2 * q, hn0[2*q], hn0[2*q+1]);
            }
            if (doL1) {
                float* d1 = gh1 + (size_t)((e + 1) & 1) * 131072 + (size_t)(rb0 + lane) * 256 + ik * HPB;
                #pragma unroll
                for (int q = 0; q < 4; ++q) stg_coh2(d1 + 2 * q, hn1[2*q], hn1[2*q+1]);
            }
        }

        // ===== fence-free device barrier (2-level tree through IF$) =====
        if (tid == 0) {
            asm volatile("s_waitcnt vmcnt(0)" ::: "memory");   // h-stores complete at IF$
            unsigned* leaf = bar + (blockIdx.x >> 3) * 32;
            unsigned* root = bar + 1024;
            unsigned pos = __hip_atomic_fetch_add(leaf, 1u, __ATOMIC_RELAXED, __HIP_MEMORY_SCOPE_AGENT);
            if ((pos & 7u) == 7u)
                __hip_atomic_fetch_add(root, 1u, __ATOMIC_RELAXED, __HIP_MEMORY_SCOPE_AGENT);
            unsigned tgt = 32u * (unsigned)(e + 1);
            while (__hip_atomic_load(root, __ATOMIC_RELAXED, __HIP_MEMORY_SCOPE_AGENT) < tgt)
                __builtin_amdgcn_s_sleep(4);
        }
        __syncthreads();
    }

    // ===== head: y[b] = h1[255] . Wlin + blin  (h1[255] in slot 1) =====
    if (ik == 0) {
        const float* hf = gh1 + 131072;
        int r = tid >> 2, q = tid & 3;
        const float* hr = hf + (size_t)(rb0 + r) * 256 + q * 64;
        float sacc = 0.f;
        #pragma unroll 1
        for (int m = 0; m < 32; ++m) {
            float2 v = ldg_coh2(hr + 2 * m);
            sacc += v.x * Wlin[q * 64 + 2 * m] + v.y * Wlin[q * 64 + 2 * m + 1];
        }
        sacc += __shfl_down(sacc, 2, 4);
        sacc += __shfl_down(sacc, 1, 4);
        if (q == 0) out[rb0 + r] = sacc + blin[0];
    }
}

// ---------------------------------------------------------------------------
extern "C" void kernel_launch(void* const* d_in, const int* in_sizes, int n_in,
                              void* d_out, int out_size, void* d_ws, size_t ws_size,
                              hipStream_t stream) {
    const float* x     = (const float*)d_in[0];
    const float* W_ih0 = (const float*)d_in[1];
    const float* W_hh0 = (const float*)d_in[2];
    const float* b_ih0 = (const float*)d_in[3];
    const float* b_hh0 = (const float*)d_in[4];
    const float* W_ih1 = (const float*)d_in[5];
    const float* W_hh1 = (const float*)d_in[6];
    const float* b_ih1 = (const float*)d_in[7];
    const float* b_hh1 = (const float*)d_in[8];
    const float* W_lin = (const float*)d_in[9];
    const float* b_lin = (const float*)d_in[10];
    float* out = (float*)d_out;
    float* ws  = (float*)d_ws;

    // zero h ring buffers + barrier counters (ws is re-poisoned before every launch)
    hipMemsetAsync((char*)d_ws + (size_t)OFF_H0 * 4, 0,
                   (size_t)(OFF_BAR - OFF_H0 + 2048) * 4, stream);

    transpose_gi<<<1024, 256, 0, stream>>>(W_hh0, ws + OFF_AHH0, 256);
    transpose_gi<<<1024, 256, 0, stream>>>(W_ih1, ws + OFF_AIH1, 256);
    transpose_gi<<<1024, 256, 0, stream>>>(W_hh1, ws + OFF_AHH1, 256);
    transpose_gi<<<40,   256, 0, stream>>>(W_ih0, ws + OFF_AIH0, 10);

    lstm_pers<<<NB, 256, 0, stream>>>(x, b_ih0, b_hh0, b_ih1, b_hh1,
                                      W_lin, b_lin, ws, out);
}

// Round 4
// 5764.152 us; speedup vs baseline: 3.2935x; 2.9649x over previous
//
#include <hip/hip_runtime.h>
#include <math.h>

#define HID 256
#define TT  256
#define BB  512
#define RPB 64      // batch rows per block (ib = blockIdx & 7)
#define HPB 8       // hidden units per block (ik = blockIdx >> 3)
#define CPB 32      // gate-cols per block

// ws dword offsets
#define OFF_A0   0          // Ahh0 [256][1024] gate-interleaved
#define OFF_A1   262144     // Aih1
#define OFF_A2   524288     // Ahh1
#define OFF_AX   786432     // Aih0 [10][1024]
#define OFF_H0   802816     // [2 slots][256 k][512 b]
#define OFF_H1   1064960
#define OFF_FLG  1327104    // cnt[(e*8+ib)*16], 257*8*16 dw

// LDS dword offsets (132 KB static, 1 block/CU by design)
#define L_WA   0            // [256][32]
#define L_WB   8192
#define L_WC   16384
#define L_WX   24576        // [10][32]
#define L_BIAS 24896        // [64]
#define L_XS   24960        // [10][64]
#define L_HQ0  25600        // [64 k][64 r]  (current k-quarter)
#define L_HQ1  29696
#define L_TOT  33792
#define L_RED  24960        // overlay: reduce scratch, stride-65 slots
#define L_HF   29184        // overlay: h finals [2][8 u][64 r]

typedef unsigned long long ull;
typedef float4 f4;

// ---------------------------------------------------------------------------
__global__ void transpose_gi(const float* __restrict__ W, float* __restrict__ A, int K) {
    int idx = blockIdx.x * 256 + threadIdx.x;
    if (idx < K * 1024) {
        int kk = idx >> 10;
        int r  = idx & 1023;
        int k  = r >> 2;
        int g  = r & 3;
        A[idx] = W[(g * 256 + k) * K + kk];
    }
}

__device__ __forceinline__ float sigf(float x)     { return 1.0f / (1.0f + __expf(-x)); }
__device__ __forceinline__ float tanhfast(float x) { return 1.0f - 2.0f / (__expf(2.0f * x) + 1.0f); }

__device__ __forceinline__ ull ldg_coh8(const float* p) {
    return __hip_atomic_load((const ull*)p, __ATOMIC_RELAXED, __HIP_MEMORY_SCOPE_AGENT);
}
__device__ __forceinline__ void stg_coh8(float* p, float2 v) {
    ull u; __builtin_memcpy(&u, &v, 8);
    __hip_atomic_store((ull*)p, u, __ATOMIC_RELAXED, __HIP_MEMORY_SCOPE_AGENT);
}
__device__ __forceinline__ float ldg_coh4(const float* p) {
    unsigned u = __hip_atomic_load((const unsigned*)p, __ATOMIC_RELAXED, __HIP_MEMORY_SCOPE_AGENT);
    return __uint_as_float(u);
}

__device__ __forceinline__ void fma8(float* acc, float h, const f4& w0, const f4& w1) {
    acc[0] += h * w0.x; acc[1] += h * w0.y; acc[2] += h * w0.z; acc[3] += h * w0.w;
    acc[4] += h * w1.x; acc[5] += h * w1.y; acc[6] += h * w1.z; acc[7] += h * w1.w;
}

// ---------------------------------------------------------------------------
// Flow-synced persistent 2-layer LSTM. 256 blocks (1/CU) x 256 threads.
// Block (ib,ik): 64 batch rows x 8 hidden units. Weights LDS-resident (96 KB).
// Thread tile: 4 rows x 8 cols; waves split k 4-way (16 k per staged quarter).
// h exchanged [k][b]-major via 8B agent atomics; per-row-group flag sync.
// ---------------------------------------------------------------------------
__global__ __launch_bounds__(256, 1)
void lstm_flow(const float* __restrict__ x,
               const float* __restrict__ bih0, const float* __restrict__ bhh0,
               const float* __restrict__ bih1, const float* __restrict__ bhh1,
               const float* __restrict__ Wlin, const float* __restrict__ blin,
               float* __restrict__ ws, float* __restrict__ out)
{
    __shared__ float lds[L_TOT];

    const int tid  = threadIdx.x;
    const int lane = tid & 63;
    const int wv   = __builtin_amdgcn_readfirstlane(tid >> 6);
    const int ib   = blockIdx.x & 7;
    const int ik   = blockIdx.x >> 3;
    const int rb0  = ib * RPB;
    const int rt   = lane & 15;          // row-tile: rows rt*4 .. rt*4+4
    const int ct   = lane >> 4;          // col-tile: cols ct*8 .. ct*8+8

    float* gh0 = ws + OFF_H0;
    float* gh1 = ws + OFF_H1;
    unsigned* flg = (unsigned*)(ws + OFF_FLG);

    // ---- one-time: stage W slices + bias into LDS ----
    {
        const float* A0 = ws + OFF_A0 + ik * CPB;
        const float* A1 = ws + OFF_A1 + ik * CPB;
        const float* A2 = ws + OFF_A2 + ik * CPB;
        int kk0 = tid >> 3, dq = (tid & 7) * 4;
        #pragma unroll
        for (int j = 0; j < 8; ++j) {
            int k = kk0 + j * 32;
            *(f4*)(lds + L_WA + k * 32 + dq) = *(const f4*)(A0 + (size_t)k * 1024 + dq);
            *(f4*)(lds + L_WB + k * 32 + dq) = *(const f4*)(A1 + (size_t)k * 1024 + dq);
            *(f4*)(lds + L_WC + k * 32 + dq) = *(const f4*)(A2 + (size_t)k * 1024 + dq);
        }
        if (tid < 80) {
            const float* AXp = ws + OFF_AX + ik * CPB;
            int i = tid >> 3;
            *(f4*)(lds + L_WX + i * 32 + dq) = *(const f4*)(AXp + (size_t)i * 1024 + dq);
        }
        if (tid < 64) {
            int half = tid >> 5, c = tid & 31, u = c >> 2, g = c & 3;
            int idx = g * 256 + ik * HPB + u;
            lds[L_BIAS + tid] = half ? (bih1[idx] + bhh1[idx]) : (bih0[idx] + bhh0[idx]);
        }
    }

    float c0s[8], c1s[8];
    #pragma unroll
    for (int u = 0; u < 8; ++u) { c0s[u] = 0.f; c1s[u] = 0.f; }

    const int kq_hi = tid >> 5;   // 0..7 : k sub-row during staging
    const int mm    = tid & 31;   // batch-pair during staging

    __syncthreads();

    for (int e = 0; e <= TT; ++e) {
        // ---- wait for row-group ib's previous step ----
        if (e > 0) {
            if (tid == 0) {
                unsigned* cp = flg + ((e - 1) * 8 + ib) * 16;
                while (__hip_atomic_load(cp, __ATOMIC_RELAXED, __HIP_MEMORY_SCOPE_AGENT) < 32u)
                    __builtin_amdgcn_s_sleep(2);
            }
            __syncthreads();
        }

        const float* h0base = gh0 + (size_t)((e + 1) & 1) * 131072;  // h0[e-1]
        const float* h1base = gh1 + (size_t)(e & 1) * 131072;        // h1[e-2]

        ull buf[16];
        // ---- stage quarter 0 (+ x slice) ----
        {
            #pragma unroll
            for (int j = 0; j < 8; ++j) {
                int k = j * 8 + kq_hi;
                buf[j]     = ldg_coh8(h0base + (size_t)k * 512 + rb0 + 2 * mm);
                buf[j + 8] = ldg_coh8(h1base + (size_t)k * 512 + rb0 + 2 * mm);
            }
            int te = (e < TT) ? e : (TT - 1);
            #pragma unroll
            for (int rr = 0; rr < 2; ++rr) {
                int idx = tid + rr * 256;
                if (idx < 320) {
                    int r = idx / 5, j2 = idx - r * 5;
                    float2 v = *(const float2*)(x + (size_t)(rb0 + r) * 2560 + te * 10 + 2 * j2);
                    lds[L_XS + (2 * j2) * 64 + r]     = v.x;
                    lds[L_XS + (2 * j2 + 1) * 64 + r] = v.y;
                }
            }
            #pragma unroll
            for (int j = 0; j < 8; ++j) {
                int k = j * 8 + kq_hi;
                *(float2*)(lds + L_HQ0 + k * 64 + 2 * mm) = *(float2*)&buf[j];
                *(float2*)(lds + L_HQ1 + k * 64 + 2 * mm) = *(float2*)&buf[j + 8];
            }
        }
        __syncthreads();

        float a0[32], a1[32];
        #pragma unroll
        for (int c = 0; c < 32; ++c) { a0[c] = 0.f; a1[c] = 0.f; }

        // ---- 4 staged k-quarters; prefetch next in VGPRs during gemm ----
        for (int q = 0; q < 4; ++q) {
            if (q < 3) {
                #pragma unroll
                for (int j = 0; j < 8; ++j) {
                    int k = (q + 1) * 64 + j * 8 + kq_hi;
                    buf[j]     = ldg_coh8(h0base + (size_t)k * 512 + rb0 + 2 * mm);
                    buf[j + 8] = ldg_coh8(h1base + (size_t)k * 512 + rb0 + 2 * mm);
                }
            }
            #pragma unroll 4
            for (int j = 0; j < 16; ++j) {
                int kl = wv * 16 + j;          // k within quarter
                int kg = q * 64 + kl;          // global k
                const f4 wa0 = *(const f4*)(lds + L_WA + kg * 32 + ct * 8);
                const f4 wa1 = *(const f4*)(lds + L_WA + kg * 32 + ct * 8 + 4);
                const f4 wb0 = *(const f4*)(lds + L_WB + kg * 32 + ct * 8);
                const f4 wb1 = *(const f4*)(lds + L_WB + kg * 32 + ct * 8 + 4);
                const f4 wc0 = *(const f4*)(lds + L_WC + kg * 32 + ct * 8);
                const f4 wc1 = *(const f4*)(lds + L_WC + kg * 32 + ct * 8 + 4);
                const f4 h0v = *(const f4*)(lds + L_HQ0 + kl * 64 + rt * 4);
                const f4 h1v = *(const f4*)(lds + L_HQ1 + kl * 64 + rt * 4);
                fma8(a0 + 0,  h0v.x, wa0, wa1); fma8(a0 + 8,  h0v.y, wa0, wa1);
                fma8(a0 + 16, h0v.z, wa0, wa1); fma8(a0 + 24, h0v.w, wa0, wa1);
                fma8(a1 + 0,  h0v.x, wb0, wb1); fma8(a1 + 8,  h0v.y, wb0, wb1);
                fma8(a1 + 16, h0v.z, wb0, wb1); fma8(a1 + 24, h0v.w, wb0, wb1);
                fma8(a1 + 0,  h1v.x, wc0, wc1); fma8(a1 + 8,  h1v.y, wc0, wc1);
                fma8(a1 + 16, h1v.z, wc0, wc1); fma8(a1 + 24, h1v.w, wc0, wc1);
            }
            if (q == 0) {   // x contribution (K=10), split across waves
                #pragma unroll 1
                for (int i = wv; i < 10; i += 4) {
                    const f4 xw0 = *(const f4*)(lds + L_WX + i * 32 + ct * 8);
                    const f4 xw1 = *(const f4*)(lds + L_WX + i * 32 + ct * 8 + 4);
                    const f4 xv  = *(const f4*)(lds + L_XS + i * 64 + rt * 4);
                    fma8(a0 + 0,  xv.x, xw0, xw1); fma8(a0 + 8,  xv.y, xw0, xw1);
                    fma8(a0 + 16, xv.z, xw0, xw1); fma8(a0 + 24, xv.w, xw0, xw1);
                }
            }
            __syncthreads();            // done reading this quarter
            if (q < 3) {
                #pragma unroll
                for (int j = 0; j < 8; ++j) {
                    int k = j * 8 + kq_hi;
                    *(float2*)(lds + L_HQ0 + k * 64 + 2 * mm) = *(float2*)&buf[j];
                    *(float2*)(lds + L_HQ1 + k * 64 + 2 * mm) = *(float2*)&buf[j + 8];
                }
                __syncthreads();
            }
        }

        // ---- cross-wave k reduction 4 -> 2 -> 1 (stride-65 scratch) ----
        if (wv >= 2) {
            float* d = lds + L_RED + (size_t)((wv - 2) * 64 + lane) * 65;
            #pragma unroll
            for (int c4 = 0; c4 < 8; ++c4) {
                *(f4*)(d + 4 * c4)      = make_float4(a0[4*c4], a0[4*c4+1], a0[4*c4+2], a0[4*c4+3]);
                *(f4*)(d + 32 + 4 * c4) = make_float4(a1[4*c4], a1[4*c4+1], a1[4*c4+2], a1[4*c4+3]);
            }
        }
        __syncthreads();
        if (wv < 2) {
            const float* s = lds + L_RED + (size_t)(wv * 64 + lane) * 65;
            #pragma unroll
            for (int c4 = 0; c4 < 8; ++c4) {
                f4 t0 = *(const f4*)(s + 4 * c4);
                f4 t1 = *(const f4*)(s + 32 + 4 * c4);
                a0[4*c4] += t0.x; a0[4*c4+1] += t0.y; a0[4*c4+2] += t0.z; a0[4*c4+3] += t0.w;
                a1[4*c4] += t1.x; a1[4*c4+1] += t1.y; a1[4*c4+2] += t1.z; a1[4*c4+3] += t1.w;
            }
        }
        __syncthreads();
        if (wv == 1) {
            float* d = lds + L_RED + (size_t)lane * 65;
            #pragma unroll
            for (int c4 = 0; c4 < 8; ++c4) {
                *(f4*)(d + 4 * c4)      = make_float4(a0[4*c4], a0[4*c4+1], a0[4*c4+2], a0[4*c4+3]);
                *(f4*)(d + 32 + 4 * c4) = make_float4(a1[4*c4], a1[4*c4+1], a1[4*c4+2], a1[4*c4+3]);
            }
        }
        __syncthreads();

        // ---- eltwise on wave 0; finals -> LDS ----
        if (wv == 0) {
            const float* s = lds + L_RED + (size_t)lane * 65;
            #pragma unroll
            for (int c4 = 0; c4 < 8; ++c4) {
                f4 t0 = *(const f4*)(s + 4 * c4);
                f4 t1 = *(const f4*)(s + 32 + 4 * c4);
                a0[4*c4] += t0.x; a0[4*c4+1] += t0.y; a0[4*c4+2] += t0.z; a0[4*c4+3] += t0.w;
                a1[4*c4] += t1.x; a1[4*c4+1] += t1.y; a1[4*c4+2] += t1.z; a1[4*c4+3] += t1.w;
            }
            #pragma unroll
            for (int uu = 0; uu < 2; ++uu) {
                float b0i = lds[L_BIAS + ct*8 + uu*4 + 0];
                float b0f = lds[L_BIAS + ct*8 + uu*4 + 1];
                float b0g = lds[L_BIAS + ct*8 + uu*4 + 2];
                float b0o = lds[L_BIAS + ct*8 + uu*4 + 3];
                float b1i = lds[L_BIAS + 32 + ct*8 + uu*4 + 0];
                float b1f = lds[L_BIAS + 32 + ct*8 + uu*4 + 1];
                float b1g = lds[L_BIAS + 32 + ct*8 + uu*4 + 2];
                float b1o = lds[L_BIAS + 32 + ct*8 + uu*4 + 3];
                #pragma unroll
                for (int m = 0; m < 4; ++m) {
                    int ci = m * 8 + uu * 4;
                    float cn = sigf(a0[ci+1] + b0f) * c0s[m*2+uu]
                             + sigf(a0[ci+0] + b0i) * tanhfast(a0[ci+2] + b0g);
                    c0s[m*2+uu] = cn;
                    lds[L_HF + (ct*2+uu)*64 + rt*4 + m] = sigf(a0[ci+3] + b0o) * tanhfast(cn);
                    if (e > 0) {
                        float cn1 = sigf(a1[ci+1] + b1f) * c1s[m*2+uu]
                                  + sigf(a1[ci+0] + b1i) * tanhfast(a1[ci+2] + b1g);
                        c1s[m*2+uu] = cn1;
                        lds[L_HF + 512 + (ct*2+uu)*64 + rt*4 + m] = sigf(a1[ci+3] + b1o) * tanhfast(cn1);
                    }
                }
            }
        }
        __syncthreads();

        // ---- coalesced full-line h stores ([k][b]-major), all threads ----
        {
            int u = tid >> 5, m2 = tid & 31;
            if (e < TT) {
                float2 v = *(float2*)(lds + L_HF + u * 64 + 2 * m2);
                stg_coh8(gh0 + (size_t)(e & 1) * 131072 + (size_t)(ik*8+u) * 512 + rb0 + 2*m2, v);
            }
            if (e > 0) {
                float2 v = *(float2*)(lds + L_HF + 512 + u * 64 + 2 * m2);
                stg_coh8(gh1 + (size_t)((e + 1) & 1) * 131072 + (size_t)(ik*8+u) * 512 + rb0 + 2*m2, v);
            }
        }
        asm volatile("s_waitcnt vmcnt(0)" ::: "memory");
        __syncthreads();   // all waves' stores drained (compiler adds full waitcnt)
        if (tid == 0)
            __hip_atomic_fetch_add(flg + (e * 8 + ib) * 16, 1u,
                                   __ATOMIC_RELAXED, __HIP_MEMORY_SCOPE_AGENT);
    }

    // ---- head: y[b] = h1[255] . Wlin + blin  (slot 1, [k][b]-major) ----
    if (ik == 0) {
        if (tid == 0) {
            unsigned* cp = flg + (TT * 8 + ib) * 16;
            while (__hip_atomic_load(cp, __ATOMIC_RELAXED, __HIP_MEMORY_SCOPE_AGENT) < 32u)
                __builtin_amdgcn_s_sleep(2);
        }
        __syncthreads();
        const float* hf = gh1 + 131072;
        int r = tid >> 2, q4 = tid & 3;
        float sacc = 0.f;
        #pragma unroll 1
        for (int kk = 0; kk < 64; ++kk) {
            int k = q4 * 64 + kk;
            sacc += ldg_coh4(hf + (size_t)k * 512 + rb0 + r) * Wlin[k];
        }
        sacc += __shfl_down(sacc, 2, 4);
        sacc += __shfl_down(sacc, 1, 4);
        if (q4 == 0) out[rb0 + r] = sacc + blin[0];
    }
}

// ---------------------------------------------------------------------------
extern "C" void kernel_launch(void* const* d_in, const int* in_sizes, int n_in,
                              void* d_out, int out_size, void* d_ws, size_t ws_size,
                              hipStream_t stream) {
    const float* x     = (const float*)d_in[0];
    const float* W_ih0 = (const float*)d_in[1];
    const float* W_hh0 = (const float*)d_in[2];
    const float* b_ih0 = (const float*)d_in[3];
    const float* b_hh0 = (const float*)d_in[4];
    const float* W_ih1 = (const float*)d_in[5];
    const float* W_hh1 = (const float*)d_in[6];
    const float* b_ih1 = (const float*)d_in[7];
    const float* b_hh1 = (const float*)d_in[8];
    const float* W_lin = (const float*)d_in[9];
    const float* b_lin = (const float*)d_in[10];
    float* out = (float*)d_out;
    float* ws  = (float*)d_ws;

    // zero h ring buffers + flags (ws re-poisoned before every launch)
    hipMemsetAsync((char*)d_ws + (size_t)OFF_H0 * 4, 0,
                   (size_t)(OFF_FLG + 32896 - OFF_H0) * 4, stream);

    transpose_gi<<<1024, 256, 0, stream>>>(W_hh0, ws + OFF_A0, 256);
    transpose_gi<<<1024, 256, 0, stream>>>(W_ih1, ws + OFF_A1, 256);
    transpose_gi<<<1024, 256, 0, stream>>>(W_hh1, ws + OFF_A2, 256);
    transpose_gi<<<40,   256, 0, stream>>>(W_ih0, ws + OFF_AX, 10);

    lstm_flow<<<256, 256, 0, stream>>>(x, b_ih0, b_hh0, b_ih1, b_hh1,
                                       W_lin, b_lin, ws, out);
}

// Round 6
// 3272.983 us; speedup vs baseline: 5.8003x; 1.7611x over previous
//
#include <hip/hip_runtime.h>
#include <math.h>

typedef unsigned int u32;
typedef unsigned long long u64;
typedef __attribute__((ext_vector_type(8))) short bf16x8;   // 8 bf16 = 4 VGPR
typedef __attribute__((ext_vector_type(4))) float f32x4;

#define TT 256

// ---- ws byte offsets ----
#define BOFF_WT   0ULL          // bf16 [3 mat][2 pl][8 kc][1024 n][40 kpad] = 3,932,160 B
#define BOFF_WX   3932160ULL    // fp32 [10][1024] = 40,960 B
#define BOFF_H0HI 3973120ULL    // bf16 [2 slot][512 r][256 k] = 524,288 B each
#define BOFF_H0LO 4497408ULL
#define BOFF_H1HI 5021696ULL
#define BOFF_H1LO 5545984ULL
#define BOFF_FLG  6070272ULL    // u32 [(e*8+ib)*16], 257*8*16*4 = 131,584 B

// ---------------------------------------------------------------------------
// W [1024][K] row-major -> A [K][1024] gate-interleaved fp32 (for x-gemm)
__global__ void transpose_gi(const float* __restrict__ W, float* __restrict__ A, int K) {
    int idx = blockIdx.x * 256 + threadIdx.x;
    if (idx < K * 1024) {
        int kk = idx >> 10, r = idx & 1023, k = r >> 2, g = r & 3;
        A[idx] = W[(g * 256 + k) * K + kk];
    }
}

// Split fp32 weights into hi/lo bf16 planes, MFMA B-tile layout:
// wt[((mt*2+pl)*8 + kc)*1024 + n][40] , n = gate-col (u*4+g), k within chunk 0..31
__global__ void split_w(const float* __restrict__ W0, const float* __restrict__ W1,
                        const float* __restrict__ W2, unsigned short* __restrict__ wt) {
    int idx = blockIdx.x * 256 + threadIdx.x;      // 786432 total
    int k32 = idx & 31;
    int n   = (idx >> 5) & 1023;
    int kc  = (idx >> 15) & 7;
    int mt  = idx >> 18;
    const float* W = (mt == 0) ? W0 : (mt == 1) ? W1 : W2;
    int ug = n >> 2, g = n & 3, k = kc * 32 + k32;
    float v = W[(g * 256 + ug) * 256 + k];
    u32 b = __float_as_uint(v);
    unsigned short hi = (unsigned short)(b >> 16);               // truncated hi
    float lo = v - __uint_as_float(b & 0xFFFF0000u);             // exact residual
    u32 lb = __float_as_uint(lo);
    unsigned short los = (unsigned short)((lb + 0x7FFFu + ((lb >> 16) & 1u)) >> 16);
    wt[((size_t)((mt * 2 + 0) * 8 + kc) * 1024 + n) * 40 + k32] = hi;
    wt[((size_t)((mt * 2 + 1) * 8 + kc) * 1024 + n) * 40 + k32] = los;
}

__device__ __forceinline__ float sigf(float x)     { return 1.0f / (1.0f + __expf(-x)); }
__device__ __forceinline__ float tanhfast(float x) { return 1.0f - 2.0f / (__expf(2.0f * x) + 1.0f); }

__device__ __forceinline__ u64 ldg8(const unsigned short* p) {
    return __hip_atomic_load((const u64*)(const void*)p, __ATOMIC_RELAXED, __HIP_MEMORY_SCOPE_AGENT);
}
__device__ __forceinline__ u32 ldg4(const unsigned short* p) {
    return __hip_atomic_load((const u32*)(const void*)p, __ATOMIC_RELAXED, __HIP_MEMORY_SCOPE_AGENT);
}
__device__ __forceinline__ void stg4(unsigned short* p, u32 v) {
    __hip_atomic_store((u32*)(void*)p, v, __ATOMIC_RELAXED, __HIP_MEMORY_SCOPE_AGENT);
}
__device__ __forceinline__ unsigned short bhi(float v) {
    return (unsigned short)(__float_as_uint(v) >> 16);
}
__device__ __forceinline__ unsigned short blo(float v) {
    float lo = v - __uint_as_float(__float_as_uint(v) & 0xFFFF0000u);
    u32 lb = __float_as_uint(lo);
    return (unsigned short)((lb + 0x7FFFu + ((lb >> 16) & 1u)) >> 16);
}
__device__ __forceinline__ float bff(u32 us) { return __uint_as_float(us << 16); }

union FragU { u64 q[2]; bf16x8 v; };

// ---------------------------------------------------------------------------
// MFMA persistent 2-layer LSTM. 256 blocks (1/CU) x 256 threads (4 waves).
// Block (ib,ik): 64 batch rows x 8 hidden units (32 gate cols). Weights in LDS
// as bf16 hi/lo B-tiles. h ring in IF$ as bf16 hi/lo planes [slot][r][k] -> A
// fragments loaded DIRECTLY from global (agent atomics, no LDS round trip).
// Wave wv owns row-tile rt=wv (16 rows), both 16-col tiles, both layers:
// 4 C-tiles, 24 mfma per k32-chunk (4 split-terms x 3 matrices x 2 ct).
// ---------------------------------------------------------------------------
__global__ __launch_bounds__(256, 1)
void lstm_mfma(const float* __restrict__ x,
               const float* __restrict__ bih0, const float* __restrict__ bhh0,
               const float* __restrict__ bih1, const float* __restrict__ bhh1,
               const float* __restrict__ Wlin, const float* __restrict__ blin,
               char* __restrict__ wsb, float* __restrict__ out)
{
    __shared__ unsigned short lw[61440];   // B-tiles: [6 pl][8 kc][32 n][40 kpad]
    __shared__ float fsh[5316];            // Wx [10][32] | xs [10][64] | CS [2][64][33]
    float* ldsWx = fsh;
    float* xs    = fsh + 320;
    float* CS    = fsh + 960;

    const int tid  = threadIdx.x;
    const int lane = tid & 63;
    const int wv   = __builtin_amdgcn_readfirstlane(tid >> 6);
    const int quad = lane >> 4;
    const int l15  = lane & 15;
    const int ib   = blockIdx.x & 7;
    const int ik   = blockIdx.x >> 3;
    const int rb0  = ib * 64;

    const unsigned short* wt = (const unsigned short*)(wsb + BOFF_WT);
    const float* gWx = (const float*)(wsb + BOFF_WX);
    unsigned short* h0hi = (unsigned short*)(wsb + BOFF_H0HI);
    unsigned short* h0lo = (unsigned short*)(wsb + BOFF_H0LO);
    unsigned short* h1hi = (unsigned short*)(wsb + BOFF_H1HI);
    unsigned short* h1lo = (unsigned short*)(wsb + BOFF_H1LO);
    u32* flg = (u32*)(wsb + BOFF_FLG);

    // ---- one-time: weight B-tiles (this block's 32-col slice) into LDS ----
    // 48 plane-chunks x [32 n][40 k] = 48 x 1280 shorts = 48 x 160 b128 units.
    #pragma unroll 1
    for (int j = 0; j < 30; ++j) {
        int i16 = tid + j * 256;               // 0..7679 (b128 units)
        int ch  = i16 / 160;                   // plane-chunk 0..47
        int wi  = i16 - ch * 160;              // b128 unit within chunk 0..159
        size_t src = (size_t)ch * 40960 + (size_t)ik * 1280 + (size_t)wi * 8;
        *(ulonglong2*)(lw + (size_t)ch * 1280 + (size_t)wi * 8) =
            *(const ulonglong2*)(wt + src);
    }
    for (int n = tid; n < 320; n += 256)
        ldsWx[n] = gWx[(n >> 5) * 1024 + ik * 32 + (n & 31)];

    // biases in regs (eltwise mapping: r = tid&63, u2 = tid>>6)
    float b0r[8], b1r[8];
    {
        int u2 = tid >> 6;
        #pragma unroll
        for (int j = 0; j < 8; ++j) {
            int ul = u2 * 2 + (j >> 2), g = j & 3;
            int gi = g * 256 + ik * 8 + ul;
            b0r[j] = bih0[gi] + bhh0[gi];
            b1r[j] = bih1[gi] + bhh1[gi];
        }
    }
    float c0s[2] = {0.f, 0.f}, c1s[2] = {0.f, 0.f};
    const int arow = rb0 + wv * 16 + l15;      // absolute batch row for A-frags
    const bf16x8* bw = (const bf16x8*)lw;

    __syncthreads();

    for (int e = 0; e <= TT; ++e) {
        // ---- stage x[te] (h-independent: overlaps flag wait) ----
        {
            int te = (e < TT) ? e : (TT - 1);
            #pragma unroll
            for (int rr = 0; rr < 2; ++rr) {
                int idx = tid + rr * 256;
                if (idx < 320) {
                    int r = idx / 5, j2 = idx - r * 5;
                    float2 v = *(const float2*)(x + (size_t)(rb0 + r) * 2560 + te * 10 + 2 * j2);
                    xs[(2 * j2) * 64 + r]     = v.x;
                    xs[(2 * j2 + 1) * 64 + r] = v.y;
                }
            }
        }
        __syncthreads();

        // ---- x contribution + bias for this thread's 8 gate-cols ----
        float xc[8];
        {
            int r = tid & 63, u2 = tid >> 6;
            #pragma unroll
            for (int j = 0; j < 8; ++j) xc[j] = b0r[j];
            #pragma unroll
            for (int i = 0; i < 10; ++i) {
                float xv = xs[i * 64 + r];
                #pragma unroll
                for (int j = 0; j < 8; ++j)
                    xc[j] += xv * ldsWx[i * 32 + u2 * 8 + j];
            }
        }

        // ---- wait for row-group's previous step ----
        if (e > 0) {
            if (tid == 0) {
                u32* cp = flg + ((e - 1) * 8 + ib) * 16;
                while (__hip_atomic_load(cp, __ATOMIC_RELAXED, __HIP_MEMORY_SCOPE_AGENT) < 32u)
                    __builtin_amdgcn_s_sleep(2);
            }
            __syncthreads();
        }

        // ---- gemm: 8 k32-chunks, A-frags direct from IF$ ring, B from LDS ----
        const unsigned short* pl0 = h0hi + ((size_t)((e + 1) & 1) * 512 + arow) * 256;
        const unsigned short* pl1 = h0lo + ((size_t)((e + 1) & 1) * 512 + arow) * 256;
        const unsigned short* pl2 = h1hi + ((size_t)(e & 1) * 512 + arow) * 256;
        const unsigned short* pl3 = h1lo + ((size_t)(e & 1) * 512 + arow) * 256;

        f32x4 C0a[2], C1a[2];
        #pragma unroll
        for (int ct = 0; ct < 2; ++ct) {
            C0a[ct] = (f32x4){0.f, 0.f, 0.f, 0.f};
            C1a[ct] = (f32x4){0.f, 0.f, 0.f, 0.f};
        }

        u64 bA[2][8];
        #define ISSUE_A(b, q) { int ke = (q) * 32 + quad * 8;            \
            bA[b][0] = ldg8(pl0 + ke); bA[b][1] = ldg8(pl0 + ke + 4);    \
            bA[b][2] = ldg8(pl1 + ke); bA[b][3] = ldg8(pl1 + ke + 4);    \
            bA[b][4] = ldg8(pl2 + ke); bA[b][5] = ldg8(pl2 + ke + 4);    \
            bA[b][6] = ldg8(pl3 + ke); bA[b][7] = ldg8(pl3 + ke + 4); }
        ISSUE_A(0, 0)
        ISSUE_A(1, 1)

        #pragma unroll
        for (int q = 0; q < 8; ++q) {
            const int b = q & 1;
            FragU a0h, a0l, a1h, a1l;
            a0h.q[0] = bA[b][0]; a0h.q[1] = bA[b][1];
            a0l.q[0] = bA[b][2]; a0l.q[1] = bA[b][3];
            a1h.q[0] = bA[b][4]; a1h.q[1] = bA[b][5];
            a1l.q[0] = bA[b][6]; a1l.q[1] = bA[b][7];
            if (q < 6) ISSUE_A(b, q + 2)
            #pragma unroll
            for (int ct = 0; ct < 2; ++ct) {
                const int rbase = ct * 16 + l15;
                bf16x8 wah = bw[5 * ((0 * 8 + q) * 32 + rbase) + quad];  // hh0 hi
                bf16x8 wal = bw[5 * ((1 * 8 + q) * 32 + rbase) + quad];  // hh0 lo
                bf16x8 wbh = bw[5 * ((2 * 8 + q) * 32 + rbase) + quad];  // ih1 hi
                bf16x8 wbl = bw[5 * ((3 * 8 + q) * 32 + rbase) + quad];  // ih1 lo
                bf16x8 wch = bw[5 * ((4 * 8 + q) * 32 + rbase) + quad];  // hh1 hi
                bf16x8 wcl = bw[5 * ((5 * 8 + q) * 32 + rbase) + quad];  // hh1 lo
                C0a[ct] = __builtin_amdgcn_mfma_f32_16x16x32_bf16(a0h.v, wah, C0a[ct], 0, 0, 0);
                C0a[ct] = __builtin_amdgcn_mfma_f32_16x16x32_bf16(a0h.v, wal, C0a[ct], 0, 0, 0);
                C0a[ct] = __builtin_amdgcn_mfma_f32_16x16x32_bf16(a0l.v, wah, C0a[ct], 0, 0, 0);
                C0a[ct] = __builtin_amdgcn_mfma_f32_16x16x32_bf16(a0l.v, wal, C0a[ct], 0, 0, 0);
                C1a[ct] = __builtin_amdgcn_mfma_f32_16x16x32_bf16(a0h.v, wbh, C1a[ct], 0, 0, 0);
                C1a[ct] = __builtin_amdgcn_mfma_f32_16x16x32_bf16(a0h.v, wbl, C1a[ct], 0, 0, 0);
                C1a[ct] = __builtin_amdgcn_mfma_f32_16x16x32_bf16(a0l.v, wbh, C1a[ct], 0, 0, 0);
                C1a[ct] = __builtin_amdgcn_mfma_f32_16x16x32_bf16(a0l.v, wbl, C1a[ct], 0, 0, 0);
                C1a[ct] = __builtin_amdgcn_mfma_f32_16x16x32_bf16(a1h.v, wch, C1a[ct], 0, 0, 0);
                C1a[ct] = __builtin_amdgcn_mfma_f32_16x16x32_bf16(a1h.v, wcl, C1a[ct], 0, 0, 0);
                C1a[ct] = __builtin_amdgcn_mfma_f32_16x16x32_bf16(a1l.v, wch, C1a[ct], 0, 0, 0);
                C1a[ct] = __builtin_amdgcn_mfma_f32_16x16x32_bf16(a1l.v, wcl, C1a[ct], 0, 0, 0);
            }
        }
        #undef ISSUE_A

        // ---- C/D frags -> scratch (D: col=lane&15, row=quad*4+reg; m89-verified) ----
        #pragma unroll
        for (int ct = 0; ct < 2; ++ct)
            #pragma unroll
            for (int reg = 0; reg < 4; ++reg) {
                int rr = wv * 16 + quad * 4 + reg;
                CS[rr * 33 + ct * 16 + l15]        = C0a[ct][reg];
                CS[2112 + rr * 33 + ct * 16 + l15] = C1a[ct][reg];
            }
        __syncthreads();

        // ---- eltwise on ALL waves (thread = row x 2 units); pack + store ----
        {
            int r = tid & 63, u2 = tid >> 6;
            if (e < TT) {
                float h0n[2];
                #pragma unroll
                for (int s = 0; s < 2; ++s) {
                    int c4 = (u2 * 2 + s) * 4;
                    float gi = CS[r * 33 + c4 + 0] + xc[s * 4 + 0];
                    float gf = CS[r * 33 + c4 + 1] + xc[s * 4 + 1];
                    float gg = CS[r * 33 + c4 + 2] + xc[s * 4 + 2];
                    float go = CS[r * 33 + c4 + 3] + xc[s * 4 + 3];
                    float cn = sigf(gf) * c0s[s] + sigf(gi) * tanhfast(gg);
                    c0s[s] = cn;
                    h0n[s] = sigf(go) * tanhfast(cn);
                }
                size_t el = ((size_t)(e & 1) * 512 + rb0 + r) * 256 + ik * 8 + u2 * 2;
                stg4(h0hi + el, (u32)bhi(h0n[0]) | ((u32)bhi(h0n[1]) << 16));
                stg4(h0lo + el, (u32)blo(h0n[0]) | ((u32)blo(h0n[1]) << 16));
            }
            if (e > 0) {
                float h1n[2];
                #pragma unroll
                for (int s = 0; s < 2; ++s) {
                    int c4 = (u2 * 2 + s) * 4;
                    float gi = CS[2112 + r * 33 + c4 + 0] + b1r[s * 4 + 0];
                    float gf = CS[2112 + r * 33 + c4 + 1] + b1r[s * 4 + 1];
                    float gg = CS[2112 + r * 33 + c4 + 2] + b1r[s * 4 + 2];
                    float go = CS[2112 + r * 33 + c4 + 3] + b1r[s * 4 + 3];
                    float cn = sigf(gf) * c1s[s] + sigf(gi) * tanhfast(gg);
                    c1s[s] = cn;
                    h1n[s] = sigf(go) * tanhfast(cn);
                }
                size_t el = ((size_t)((e + 1) & 1) * 512 + rb0 + r) * 256 + ik * 8 + u2 * 2;
                stg4(h1hi + el, (u32)bhi(h1n[0]) | ((u32)bhi(h1n[1]) << 16));
                stg4(h1lo + el, (u32)blo(h1n[0]) | ((u32)blo(h1n[1]) << 16));
            }
        }
        asm volatile("s_waitcnt vmcnt(0)" ::: "memory");
        __syncthreads();
        if (tid == 0)
            __hip_atomic_fetch_add(flg + (e * 8 + ib) * 16, 1u,
                                   __ATOMIC_RELAXED, __HIP_MEMORY_SCOPE_AGENT);
    }

    // ---- head: y[b] = h1[255] . Wlin + blin (slot 1; reconstruct hi+lo) ----
    if (ik == 0) {
        if (tid == 0) {
            u32* cp = flg + (TT * 8 + ib) * 16;
            while (__hip_atomic_load(cp, __ATOMIC_RELAXED, __HIP_MEMORY_SCOPE_AGENT) < 32u)
                __builtin_amdgcn_s_sleep(2);
        }
        __syncthreads();
        int r = tid >> 2, q4 = tid & 3;
        const unsigned short* ph = h1hi + ((size_t)512 + rb0 + r) * 256;
        const unsigned short* pl = h1lo + ((size_t)512 + rb0 + r) * 256;
        float sacc = 0.f;
        #pragma unroll 1
        for (int kk = 0; kk < 64; kk += 2) {
            int k = q4 * 64 + kk;
            u32 hw = ldg4(ph + k), lwd = ldg4(pl + k);
            sacc += (bff(hw & 0xFFFFu) + bff(lwd & 0xFFFFu)) * Wlin[k];
            sacc += (bff(hw >> 16)     + bff(lwd >> 16))     * Wlin[k + 1];
        }
        sacc += __shfl_down(sacc, 2, 4);
        sacc += __shfl_down(sacc, 1, 4);
        if (q4 == 0) out[rb0 + r] = sacc + blin[0];
    }
}

// ---------------------------------------------------------------------------
extern "C" void kernel_launch(void* const* d_in, const int* in_sizes, int n_in,
                              void* d_out, int out_size, void* d_ws, size_t ws_size,
                              hipStream_t stream) {
    const float* x     = (const float*)d_in[0];
    const float* W_ih0 = (const float*)d_in[1];
    const float* W_hh0 = (const float*)d_in[2];
    const float* b_ih0 = (const float*)d_in[3];
    const float* b_hh0 = (const float*)d_in[4];
    const float* W_ih1 = (const float*)d_in[5];
    const float* W_hh1 = (const float*)d_in[6];
    const float* b_ih1 = (const float*)d_in[7];
    const float* b_hh1 = (const float*)d_in[8];
    const float* W_lin = (const float*)d_in[9];
    const float* b_lin = (const float*)d_in[10];
    float* out = (float*)d_out;
    char* wsb  = (char*)d_ws;

    // zero h ring planes + flags (ws re-poisoned before every timed launch)
    hipMemsetAsync(wsb + BOFF_H0HI, 0, 4 * 524288 + 131584, stream);

    split_w<<<3072, 256, 0, stream>>>(W_hh0, W_ih1, W_hh1,
                                      (unsigned short*)(wsb + BOFF_WT));
    transpose_gi<<<40, 256, 0, stream>>>(W_ih0, (float*)(wsb + BOFF_WX), 10);

    lstm_mfma<<<256, 256, 0, stream>>>(x, b_ih0, b_hh0, b_ih1, b_hh1,
                                       W_lin, b_lin, wsb, out);
}

// Round 7
// 2089.381 us; speedup vs baseline: 9.0861x; 1.5665x over previous
//
#include <hip/hip_runtime.h>
#include <math.h>

typedef unsigned int u32;
typedef unsigned long long u64;
typedef __attribute__((ext_vector_type(8))) short bf16x8;   // 8 bf16 = 4 VGPR
typedef __attribute__((ext_vector_type(4))) float f32x4;

#define TT 256

// ---- ws byte offsets ----
#define BOFF_WT   0ULL          // bf16 [3 mat][2 pl][8 kc][1024 n][40 kpad] = 3,932,160 B
#define BOFF_WX   3932160ULL    // fp32 [10][1024] = 40,960 B
#define BOFF_H0HI 3973120ULL    // bf16 [2 slot][8 ib][32 ik][64 r][8 u] = 524,288 B each
#define BOFF_H0LO 4497408ULL
#define BOFF_H1HI 5021696ULL
#define BOFF_H1LO 5545984ULL
#define BOFF_FLG  6070272ULL    // u32 [(e*8+ib)*16], 257*8*16*4 = 131,584 B

// ---------------------------------------------------------------------------
// W [1024][K] row-major -> A [K][1024] gate-interleaved fp32 (for x-gemm)
__global__ void transpose_gi(const float* __restrict__ W, float* __restrict__ A, int K) {
    int idx = blockIdx.x * 256 + threadIdx.x;
    if (idx < K * 1024) {
        int kk = idx >> 10, r = idx & 1023, k = r >> 2, g = r & 3;
        A[idx] = W[(g * 256 + k) * K + kk];
    }
}

// Split fp32 weights into hi/lo bf16 planes, MFMA B-tile layout:
// wt[((mt*2+pl)*8 + kc)*1024 + n][40] , n = gate-col (u*4+g), k within chunk 0..31
__global__ void split_w(const float* __restrict__ W0, const float* __restrict__ W1,
                        const float* __restrict__ W2, unsigned short* __restrict__ wt) {
    int idx = blockIdx.x * 256 + threadIdx.x;      // 786432 total
    int k32 = idx & 31;
    int n   = (idx >> 5) & 1023;
    int kc  = (idx >> 15) & 7;
    int mt  = idx >> 18;
    const float* W = (mt == 0) ? W0 : (mt == 1) ? W1 : W2;
    int ug = n >> 2, g = n & 3, k = kc * 32 + k32;
    float v = W[(g * 256 + ug) * 256 + k];
    u32 b = __float_as_uint(v);
    unsigned short hi = (unsigned short)(b >> 16);               // truncated hi
    float lo = v - __uint_as_float(b & 0xFFFF0000u);             // exact residual
    u32 lb = __float_as_uint(lo);
    unsigned short los = (unsigned short)((lb + 0x7FFFu + ((lb >> 16) & 1u)) >> 16);
    wt[((size_t)((mt * 2 + 0) * 8 + kc) * 1024 + n) * 40 + k32] = hi;
    wt[((size_t)((mt * 2 + 1) * 8 + kc) * 1024 + n) * 40 + k32] = los;
}

__device__ __forceinline__ float sigf(float x)     { return 1.0f / (1.0f + __expf(-x)); }
__device__ __forceinline__ float tanhfast(float x) { return 1.0f - 2.0f / (__expf(2.0f * x) + 1.0f); }

__device__ __forceinline__ u64 ldg8(const unsigned short* p) {
    return __hip_atomic_load((const u64*)(const void*)p, __ATOMIC_RELAXED, __HIP_MEMORY_SCOPE_AGENT);
}
__device__ __forceinline__ u32 ldg4(const unsigned short* p) {
    return __hip_atomic_load((const u32*)(const void*)p, __ATOMIC_RELAXED, __HIP_MEMORY_SCOPE_AGENT);
}
__device__ __forceinline__ void stg4(unsigned short* p, u32 v) {
    __hip_atomic_store((u32*)(void*)p, v, __ATOMIC_RELAXED, __HIP_MEMORY_SCOPE_AGENT);
}
__device__ __forceinline__ unsigned short bhi(float v) {
    return (unsigned short)(__float_as_uint(v) >> 16);
}
__device__ __forceinline__ unsigned short blo(float v) {
    float lo = v - __uint_as_float(__float_as_uint(v) & 0xFFFF0000u);
    u32 lb = __float_as_uint(lo);
    return (unsigned short)((lb + 0x7FFFu + ((lb >> 16) & 1u)) >> 16);
}
__device__ __forceinline__ float bff(u32 us) { return __uint_as_float(us << 16); }

union FragU { u64 q[2]; bf16x8 v; };

// ---------------------------------------------------------------------------
// MFMA persistent 2-layer LSTM. 256 blocks (1/CU) x 256 threads (4 waves).
// Block (ib,ik): 64 batch rows x 8 hidden units (32 gate cols). Weights in LDS
// as bf16 hi/lo B-tiles. h ring in IF$, block-tile-major [slot][ib][ik][r][u]:
// stores are wave-contiguous full lines; A-frag loads are 16B/lane contiguous
// (k-chunk quad maps to exactly one ik-tile since k = 8*ik + u).
// Wave (rh,ch): rows rh*32..+32 (2 A-tiles), cols ch*16..+16 (1 B-tile):
// per k32-chunk: 6 B ds_reads, 16 A ldg8 (dbuf), 24 mfma.
// ---------------------------------------------------------------------------
__global__ __launch_bounds__(256, 1)
void lstm_mfma(const float* __restrict__ x,
               const float* __restrict__ bih0, const float* __restrict__ bhh0,
               const float* __restrict__ bih1, const float* __restrict__ bhh1,
               const float* __restrict__ Wlin, const float* __restrict__ blin,
               char* __restrict__ wsb, float* __restrict__ out)
{
    __shared__ unsigned short lw[61440];   // B-tiles: [6 pl][8 kc][32 n][40 kpad]
    __shared__ float fsh[5184];            // Wx [10][32] | xs [10][64] | CS [2][64][33]
    float* ldsWx = fsh;
    float* xs    = fsh + 320;
    float* CS    = fsh + 960;

    const int tid  = threadIdx.x;
    const int lane = tid & 63;
    const int wv   = __builtin_amdgcn_readfirstlane(tid >> 6);
    const int quad = lane >> 4;
    const int l15  = lane & 15;
    const int rh   = wv >> 1;              // row-half (32 rows)
    const int ch   = wv & 1;               // col-half (16 gate-cols)
    const int ib   = blockIdx.x & 7;
    const int ik   = blockIdx.x >> 3;
    const int rb0  = ib * 64;

    const unsigned short* wt = (const unsigned short*)(wsb + BOFF_WT);
    const float* gWx = (const float*)(wsb + BOFF_WX);
    unsigned short* h0hi = (unsigned short*)(wsb + BOFF_H0HI);
    unsigned short* h0lo = (unsigned short*)(wsb + BOFF_H0LO);
    unsigned short* h1hi = (unsigned short*)(wsb + BOFF_H1HI);
    unsigned short* h1lo = (unsigned short*)(wsb + BOFF_H1LO);
    u32* flg = (u32*)(wsb + BOFF_FLG);

    // ---- one-time: weight B-tiles (this block's 32-col slice) into LDS ----
    // 48 plane-chunks x [32 n][40 k] = 48 x 1280 shorts = 48 x 160 b128 units.
    #pragma unroll 1
    for (int j = 0; j < 30; ++j) {
        int i16 = tid + j * 256;               // 0..7679 (b128 units)
        int chk = i16 / 160;                   // plane-chunk 0..47
        int wi  = i16 - chk * 160;             // b128 unit within chunk
        size_t src = (size_t)chk * 40960 + (size_t)ik * 1280 + (size_t)wi * 8;
        *(ulonglong2*)(lw + (size_t)chk * 1280 + (size_t)wi * 8) =
            *(const ulonglong2*)(wt + src);
    }
    for (int n = tid; n < 320; n += 256)
        ldsWx[n] = gWx[(n >> 5) * 1024 + ik * 32 + (n & 31)];

    // biases in regs (eltwise mapping: r = tid>>2, unit-pair up = tid&3)
    float b0r[8], b1r[8];
    {
        int up = tid & 3;
        #pragma unroll
        for (int j = 0; j < 8; ++j) {
            int ul = up * 2 + (j >> 2), g = j & 3;
            int gi = g * 256 + ik * 8 + ul;
            b0r[j] = bih0[gi] + bhh0[gi];
            b1r[j] = bih1[gi] + bhh1[gi];
        }
    }
    float c0s[2] = {0.f, 0.f}, c1s[2] = {0.f, 0.f};
    const int rl0 = rh * 32 + l15;          // local row, A-tile 0 (tile1 = +16)
    const bf16x8* bw = (const bf16x8*)lw;

    __syncthreads();

    for (int e = 0; e <= TT; ++e) {
        // ---- stage x[te] ----
        {
            int te = (e < TT) ? e : (TT - 1);
            #pragma unroll
            for (int rr = 0; rr < 2; ++rr) {
                int idx = tid + rr * 256;
                if (idx < 320) {
                    int r = idx / 5, j2 = idx - r * 5;
                    float2 v = *(const float2*)(x + (size_t)(rb0 + r) * 2560 + te * 10 + 2 * j2);
                    xs[(2 * j2) * 64 + r]     = v.x;
                    xs[(2 * j2 + 1) * 64 + r] = v.y;
                }
            }
        }
        __syncthreads();

        // ---- x contribution + bias (thread = row r, unit-pair up) ----
        float xc[8];
        {
            int r = tid >> 2, up = tid & 3;
            #pragma unroll
            for (int j = 0; j < 8; ++j) xc[j] = b0r[j];
            #pragma unroll
            for (int i = 0; i < 10; ++i) {
                float xv = xs[i * 64 + r];
                #pragma unroll
                for (int j = 0; j < 8; ++j)
                    xc[j] += xv * ldsWx[i * 32 + up * 8 + j];
            }
        }

        // ---- wait for row-group's previous step ----
        if (e > 0) {
            if (tid == 0) {
                u32* cp = flg + ((e - 1) * 8 + ib) * 16;
                while (__hip_atomic_load(cp, __ATOMIC_RELAXED, __HIP_MEMORY_SCOPE_AGENT) < 32u)
                    __builtin_amdgcn_s_sleep(2);
            }
            __syncthreads();
        }

        // ---- gemm: 8 k32-chunks; A direct from IF$ tile ring, B from LDS ----
        const unsigned short* p0h = h0hi + (size_t)(((e + 1) & 1) * 8 + ib) * 16384;
        const unsigned short* p0l = h0lo + (size_t)(((e + 1) & 1) * 8 + ib) * 16384;
        const unsigned short* p1h = h1hi + (size_t)((e & 1) * 8 + ib) * 16384;
        const unsigned short* p1l = h1lo + (size_t)((e & 1) * 8 + ib) * 16384;
        const int oa0 = quad * 512 + rl0 * 8;          // A-tile0 lane offset
        const int oa1 = oa0 + 16 * 8;                  // A-tile1 (+16 rows)

        f32x4 C0[2], C1[2];
        #pragma unroll
        for (int rt = 0; rt < 2; ++rt) {
            C0[rt] = (f32x4){0.f, 0.f, 0.f, 0.f};
            C1[rt] = (f32x4){0.f, 0.f, 0.f, 0.f};
        }

        u64 bA[2][16];
        #define ISSUE_A(b, qc) { int tb = (qc) * 2048;                              \
            bA[b][0]  = ldg8(p0h + tb + oa0); bA[b][1]  = ldg8(p0h + tb + oa0 + 4); \
            bA[b][2]  = ldg8(p0l + tb + oa0); bA[b][3]  = ldg8(p0l + tb + oa0 + 4); \
            bA[b][4]  = ldg8(p1h + tb + oa0); bA[b][5]  = ldg8(p1h + tb + oa0 + 4); \
            bA[b][6]  = ldg8(p1l + tb + oa0); bA[b][7]  = ldg8(p1l + tb + oa0 + 4); \
            bA[b][8]  = ldg8(p0h + tb + oa1); bA[b][9]  = ldg8(p0h + tb + oa1 + 4); \
            bA[b][10] = ldg8(p0l + tb + oa1); bA[b][11] = ldg8(p0l + tb + oa1 + 4); \
            bA[b][12] = ldg8(p1h + tb + oa1); bA[b][13] = ldg8(p1h + tb + oa1 + 4); \
            bA[b][14] = ldg8(p1l + tb + oa1); bA[b][15] = ldg8(p1l + tb + oa1 + 4); }
        ISSUE_A(0, 0)
        ISSUE_A(1, 1)

        #pragma unroll
        for (int q = 0; q < 8; ++q) {
            const int b = q & 1;
            const int rbase = ch * 16 + l15;
            bf16x8 wah = bw[5 * ((0 * 8 + q) * 32 + rbase) + quad];  // hh0 hi
            bf16x8 wal = bw[5 * ((1 * 8 + q) * 32 + rbase) + quad];  // hh0 lo
            bf16x8 wbh = bw[5 * ((2 * 8 + q) * 32 + rbase) + quad];  // ih1 hi
            bf16x8 wbl = bw[5 * ((3 * 8 + q) * 32 + rbase) + quad];  // ih1 lo
            bf16x8 wch = bw[5 * ((4 * 8 + q) * 32 + rbase) + quad];  // hh1 hi
            bf16x8 wcl = bw[5 * ((5 * 8 + q) * 32 + rbase) + quad];  // hh1 lo
            FragU a0h, a0l, a1h, a1l;
            #pragma unroll
            for (int rt = 0; rt < 2; ++rt) {
                a0h.q[0] = bA[b][rt*8+0];  a0h.q[1] = bA[b][rt*8+1];
                a0l.q[0] = bA[b][rt*8+2];  a0l.q[1] = bA[b][rt*8+3];
                a1h.q[0] = bA[b][rt*8+4];  a1h.q[1] = bA[b][rt*8+5];
                a1l.q[0] = bA[b][rt*8+6];  a1l.q[1] = bA[b][rt*8+7];
                C0[rt] = __builtin_amdgcn_mfma_f32_16x16x32_bf16(a0h.v, wah, C0[rt], 0, 0, 0);
                C0[rt] = __builtin_amdgcn_mfma_f32_16x16x32_bf16(a0h.v, wal, C0[rt], 0, 0, 0);
                C0[rt] = __builtin_amdgcn_mfma_f32_16x16x32_bf16(a0l.v, wah, C0[rt], 0, 0, 0);
                C0[rt] = __builtin_amdgcn_mfma_f32_16x16x32_bf16(a0l.v, wal, C0[rt], 0, 0, 0);
                C1[rt] = __builtin_amdgcn_mfma_f32_16x16x32_bf16(a0h.v, wbh, C1[rt], 0, 0, 0);
                C1[rt] = __builtin_amdgcn_mfma_f32_16x16x32_bf16(a0h.v, wbl, C1[rt], 0, 0, 0);
                C1[rt] = __builtin_amdgcn_mfma_f32_16x16x32_bf16(a0l.v, wbh, C1[rt], 0, 0, 0);
                C1[rt] = __builtin_amdgcn_mfma_f32_16x16x32_bf16(a0l.v, wbl, C1[rt], 0, 0, 0);
                C1[rt] = __builtin_amdgcn_mfma_f32_16x16x32_bf16(a1h.v, wch, C1[rt], 0, 0, 0);
                C1[rt] = __builtin_amdgcn_mfma_f32_16x16x32_bf16(a1h.v, wcl, C1[rt], 0, 0, 0);
                C1[rt] = __builtin_amdgcn_mfma_f32_16x16x32_bf16(a1l.v, wch, C1[rt], 0, 0, 0);
                C1[rt] = __builtin_amdgcn_mfma_f32_16x16x32_bf16(a1l.v, wcl, C1[rt], 0, 0, 0);
            }
            if (q < 6) ISSUE_A(b, q + 2)
        }
        #undef ISSUE_A

        // ---- C/D frags -> scratch (D: col=lane&15, row=quad*4+reg) ----
        #pragma unroll
        for (int rt = 0; rt < 2; ++rt)
            #pragma unroll
            for (int reg = 0; reg < 4; ++reg) {
                int rr = rh * 32 + rt * 16 + quad * 4 + reg;
                CS[rr * 33 + ch * 16 + l15]        = C0[rt][reg];
                CS[2112 + rr * 33 + ch * 16 + l15] = C1[rt][reg];
            }
        __syncthreads();

        // ---- eltwise (thread = row x unit-pair); pack + tile-contiguous store ----
        {
            int r = tid >> 2, up = tid & 3;
            if (e < TT) {
                float h0n[2];
                #pragma unroll
                for (int s = 0; s < 2; ++s) {
                    int c4 = up * 8 + s * 4;
                    float gi = CS[r * 33 + c4 + 0] + xc[s * 4 + 0];
                    float gf = CS[r * 33 + c4 + 1] + xc[s * 4 + 1];
                    float gg = CS[r * 33 + c4 + 2] + xc[s * 4 + 2];
                    float go = CS[r * 33 + c4 + 3] + xc[s * 4 + 3];
                    float cn = sigf(gf) * c0s[s] + sigf(gi) * tanhfast(gg);
                    c0s[s] = cn;
                    h0n[s] = sigf(go) * tanhfast(cn);
                }
                size_t tb = (size_t)((e & 1) * 8 + ib) * 16384 + (size_t)ik * 512 + 2 * tid;
                stg4(h0hi + tb, (u32)bhi(h0n[0]) | ((u32)bhi(h0n[1]) << 16));
                stg4(h0lo + tb, (u32)blo(h0n[0]) | ((u32)blo(h0n[1]) << 16));
            }
            if (e > 0) {
                float h1n[2];
                #pragma unroll
                for (int s = 0; s < 2; ++s) {
                    int c4 = up * 8 + s * 4;
                    float gi = CS[2112 + r * 33 + c4 + 0] + b1r[s * 4 + 0];
                    float gf = CS[2112 + r * 33 + c4 + 1] + b1r[s * 4 + 1];
                    float gg = CS[2112 + r * 33 + c4 + 2] + b1r[s * 4 + 2];
                    float go = CS[2112 + r * 33 + c4 + 3] + b1r[s * 4 + 3];
                    float cn = sigf(gf) * c1s[s] + sigf(gi) * tanhfast(gg);
                    c1s[s] = cn;
                    h1n[s] = sigf(go) * tanhfast(cn);
                }
                size_t tb = (size_t)(((e + 1) & 1) * 8 + ib) * 16384 + (size_t)ik * 512 + 2 * tid;
                stg4(h1hi + tb, (u32)bhi(h1n[0]) | ((u32)bhi(h1n[1]) << 16));
                stg4(h1lo + tb, (u32)blo(h1n[0]) | ((u32)blo(h1n[1]) << 16));
            }
        }
        asm volatile("s_waitcnt vmcnt(0)" ::: "memory");
        __syncthreads();
        if (tid == 0)
            __hip_atomic_fetch_add(flg + (e * 8 + ib) * 16, 1u,
                                   __ATOMIC_RELAXED, __HIP_MEMORY_SCOPE_AGENT);
    }

    // ---- head: y[b] = h1[255] . Wlin + blin (slot 1, tile layout) ----
    if (ik == 0) {
        if (tid == 0) {
            u32* cp = flg + (TT * 8 + ib) * 16;
            while (__hip_atomic_load(cp, __ATOMIC_RELAXED, __HIP_MEMORY_SCOPE_AGENT) < 32u)
                __builtin_amdgcn_s_sleep(2);
        }
        __syncthreads();
        int r = tid >> 2, q4 = tid & 3;
        const unsigned short* ph = h1hi + (size_t)(1 * 8 + ib) * 16384;
        const unsigned short* pl = h1lo + (size_t)(1 * 8 + ib) * 16384;
        float sacc = 0.f;
        #pragma unroll 1
        for (int kk = 0; kk < 64; kk += 2) {
            int k = q4 * 64 + kk;
            int sa = (k >> 3) * 512 + r * 8 + (k & 7);
            u32 hw = ldg4(ph + sa), lwd = ldg4(pl + sa);
            sacc += (bff(hw & 0xFFFFu) + bff(lwd & 0xFFFFu)) * Wlin[k];
            sacc += (bff(hw >> 16)     + bff(lwd >> 16))     * Wlin[k + 1];
        }
        sacc += __shfl_down(sacc, 2, 4);
        sacc += __shfl_down(sacc, 1, 4);
        if (q4 == 0) out[rb0 + r] = sacc + blin[0];
    }
}

// ---------------------------------------------------------------------------
extern "C" void kernel_launch(void* const* d_in, const int* in_sizes, int n_in,
                              void* d_out, int out_size, void* d_ws, size_t ws_size,
                              hipStream_t stream) {
    const float* x     = (const float*)d_in[0];
    const float* W_ih0 = (const float*)d_in[1];
    const float* W_hh0 = (const float*)d_in[2];
    const float* b_ih0 = (const float*)d_in[3];
    const float* b_hh0 = (const float*)d_in[4];
    const float* W_ih1 = (const float*)d_in[5];
    const float* W_hh1 = (const float*)d_in[6];
    const float* b_ih1 = (const float*)d_in[7];
    const float* b_hh1 = (const float*)d_in[8];
    const float* W_lin = (const float*)d_in[9];
    const float* b_lin = (const float*)d_in[10];
    float* out = (float*)d_out;
    char* wsb  = (char*)d_ws;

    // zero h ring planes + flags (ws re-poisoned before every timed launch)
    hipMemsetAsync(wsb + BOFF_H0HI, 0, 4 * 524288 + 131584, stream);

    split_w<<<3072, 256, 0, stream>>>(W_hh0, W_ih1, W_hh1,
                                      (unsigned short*)(wsb + BOFF_WT));
    transpose_gi<<<40, 256, 0, stream>>>(W_ih0, (float*)(wsb + BOFF_WX), 10);

    lstm_mfma<<<256, 256, 0, stream>>>(x, b_ih0, b_hh0, b_ih1, b_hh1,
                                       W_lin, b_lin, wsb, out);
}